// Round 1
// baseline (282.905 us; speedup 1.0000x reference)
//
#include <hip/hip_runtime.h>

#define TT 4096
#define CCH 768
#define HH 64
#define BBA 8
#define MROWS (BBA*TT)   // 32768

typedef __attribute__((ext_vector_type(8))) short short8;
typedef __attribute__((ext_vector_type(4))) float floatx4;

__device__ inline ushort f2bf(float f) {
    union { float f; unsigned u; } v; v.f = f;
    unsigned r = v.u + 0x7fffu + ((v.u >> 16) & 1u);   // RNE
    return (ushort)(r >> 16);
}

// ---- Kernel 1: Wt[3][64][768] bf16, n-major, so B-fragments are contiguous 16B ----
__global__ __launch_bounds__(256) void wt_kernel(const float* __restrict__ Wq,
                                                 const float* __restrict__ Wk,
                                                 const float* __restrict__ Wv,
                                                 ushort* __restrict__ wt) {
    int idx = blockIdx.x * 256 + threadIdx.x;
    if (idx >= 3 * 64 * 768) return;
    int m = idx / (64 * 768);
    int r = idx - m * (64 * 768);
    int n = r / 768;
    int k = r - n * 768;
    const float* W = (m == 0) ? Wq : (m == 1) ? Wk : Wv;
    wt[idx] = f2bf(W[k * 64 + n]);
}

// ---- Kernel 2: fused QKV projection. 64 rows/block, N=192, K=768 in chunks of 32 ----
__global__ __launch_bounds__(256) void proj_kernel(const float* __restrict__ x,
                                                   const ushort* __restrict__ wt,
                                                   ushort* __restrict__ qb,
                                                   ushort* __restrict__ kb,
                                                   ushort* __restrict__ vb) {
    __shared__ ushort xs[64 * 40];    // pad stride 40 (20 words): rows r,r+8 alias -> 2-way (free)
    __shared__ ushort ws[192 * 40];
    const int tid = threadIdx.x;
    const int w = tid >> 6, lane = tid & 63, c = lane & 15, qd = lane >> 4;
    const int rbase = blockIdx.x * 64;
    const int sr = tid >> 2;        // 0..63
    const int sc = (tid & 3) * 8;   // 0,8,16,24

    floatx4 acc[12];
#pragma unroll
    for (int nt = 0; nt < 12; ++nt) acc[nt] = (floatx4){0.f, 0.f, 0.f, 0.f};

    for (int kc = 0; kc < CCH; kc += 32) {
        {   // stage x chunk (fp32 -> bf16)
            const float* src = &x[(size_t)(rbase + sr) * CCH + kc + sc];
            float4 f0 = *(const float4*)src;
            float4 f1 = *(const float4*)(src + 4);
            short8 xv;
            xv[0] = (short)f2bf(f0.x); xv[1] = (short)f2bf(f0.y);
            xv[2] = (short)f2bf(f0.z); xv[3] = (short)f2bf(f0.w);
            xv[4] = (short)f2bf(f1.x); xv[5] = (short)f2bf(f1.y);
            xv[6] = (short)f2bf(f1.z); xv[7] = (short)f2bf(f1.w);
            *(short8*)&xs[sr * 40 + sc] = xv;
        }
#pragma unroll
        for (int i = 0; i < 3; ++i) {   // stage Wt chunk
            int row = i * 64 + sr;
            short8 wv = *(const short8*)&wt[(size_t)row * CCH + kc + sc];
            *(short8*)&ws[row * 40 + sc] = wv;
        }
        __syncthreads();
        short8 a = *(const short8*)&xs[(w * 16 + c) * 40 + qd * 8];
#pragma unroll
        for (int nt = 0; nt < 12; ++nt) {
            short8 bfr = *(const short8*)&ws[(nt * 16 + c) * 40 + qd * 8];
            acc[nt] = __builtin_amdgcn_mfma_f32_16x16x32_bf16(a, bfr, acc[nt], 0, 0, 0);
        }
        __syncthreads();
    }
    // epilogue: C-layout row = w*16 + qd*4 + r, col = nt*16 + c
#pragma unroll
    for (int nt = 0; nt < 12; ++nt) {
        int ncol = nt * 16 + c;
        ushort* dst = (ncol < 64) ? qb : (ncol < 128) ? kb : vb;
        int h = ncol & 63;
#pragma unroll
        for (int r = 0; r < 4; ++r) {
            int rg = rbase + w * 16 + qd * 4 + r;
            dst[(size_t)rg * 64 + h] = f2bf(acc[nt][r]);
        }
    }
}

// ---- Kernel 3: flash attention. Block = 4 waves x 16 queries = 64-query tile.
// Computes S^T = K*Q^T so softmax stats live at query = lane&15 and P packs into b64 LDS writes.
// Block processes qtile pair {63-jp, jp}: constant 65 k-tile iterations -> perfect balance.
__global__ __launch_bounds__(256) void attn_kernel(const ushort* __restrict__ qb,
                                                   const ushort* __restrict__ kb,
                                                   const ushort* __restrict__ vb,
                                                   float* __restrict__ out) {
    __shared__ ushort Ks[64 * 72];      // [key][dim], pad 72 -> 2-way on b128 reads (free)
    __shared__ ushort Vt[64 * 72];      // [dim][key], pad 72
    __shared__ ushort Pl[4][1024];      // per-wave P, 16 rows x 64, XOR-swizzled 4-word granules
    const float scale = 0.03608439182435161f;   // 768^-0.5
    const int tid = threadIdx.x;
    const int w = tid >> 6, lane = tid & 63, c = lane & 15, qd = lane >> 4;
    const int b = blockIdx.x >> 5;
    const int jp = blockIdx.x & 31;
    const int sr = tid >> 2;            // K staging row
    const int sc = (tid & 3) * 16;      // K staging col
    const int vr = tid & 63;            // V staging key
    const int vc = (tid >> 6) * 16;     // V staging dim base

#pragma unroll 1
    for (int sel = 0; sel < 2; ++sel) {
        const int qt = sel ? jp : (63 - jp);
        const int qbase = qt * 64;
        const size_t growq = (size_t)(b * TT + qbase + w * 16 + c);
        short8 qf0 = *(const short8*)&qb[growq * 64 + qd * 8];        // Q[query=c][d=qd*8+j]
        short8 qf1 = *(const short8*)&qb[growq * 64 + 32 + qd * 8];
        floatx4 o[4];
#pragma unroll
        for (int nt = 0; nt < 4; ++nt) o[nt] = (floatx4){0.f, 0.f, 0.f, 0.f};
        float m_run = -__builtin_inff(), l_run = 0.f;
        const int qg = qbase + w * 16 + c;

        for (int kt = 0; kt <= qt; ++kt) {
            __syncthreads();   // protect LDS tiles from previous iteration's readers
            {   // stage K tile
                const ushort* src = &kb[((size_t)(b * TT + kt * 64 + sr)) * 64 + sc];
                short8 k0 = *(const short8*)src;
                short8 k1 = *(const short8*)(src + 8);
                *(short8*)&Ks[sr * 72 + sc] = k0;
                *(short8*)&Ks[sr * 72 + sc + 8] = k1;
            }
            {   // stage V tile transposed
                const ushort* src = &vb[((size_t)(b * TT + kt * 64 + vr)) * 64 + vc];
                short8 v0 = *(const short8*)src;
                short8 v1 = *(const short8*)(src + 8);
#pragma unroll
                for (int i = 0; i < 8; ++i) Vt[(vc + i) * 72 + vr] = (ushort)v0[i];
#pragma unroll
                for (int i = 0; i < 8; ++i) Vt[(vc + 8 + i) * 72 + vr] = (ushort)v1[i];
            }
            __syncthreads();
            // S^T[key][query]: A=K fragment, B=Q fragment
            floatx4 st[4];
#pragma unroll
            for (int mt = 0; mt < 4; ++mt) {
                short8 kf0 = *(const short8*)&Ks[(mt * 16 + c) * 72 + qd * 8];
                short8 kf1 = *(const short8*)&Ks[(mt * 16 + c) * 72 + 32 + qd * 8];
                st[mt] = (floatx4){0.f, 0.f, 0.f, 0.f};
                st[mt] = __builtin_amdgcn_mfma_f32_16x16x32_bf16(kf0, qf0, st[mt], 0, 0, 0);
                st[mt] = __builtin_amdgcn_mfma_f32_16x16x32_bf16(kf1, qf1, st[mt], 0, 0, 0);
            }
            // scale + causal mask; lane holds query c, keys kt*64 + mt*16 + qd*4 + r
            float p[16];
#pragma unroll
            for (int mt = 0; mt < 4; ++mt)
#pragma unroll
                for (int r = 0; r < 4; ++r) {
                    int key = kt * 64 + mt * 16 + qd * 4 + r;
                    float v = st[mt][r] * scale;
                    p[mt * 4 + r] = (key <= qg) ? v : -__builtin_inff();
                }
            // online softmax (row = query): local 16, then across quads
            float mx = p[0];
#pragma unroll
            for (int i = 1; i < 16; ++i) mx = fmaxf(mx, p[i]);
            mx = fmaxf(mx, __shfl_xor(mx, 16));
            mx = fmaxf(mx, __shfl_xor(mx, 32));
            float m_new = fmaxf(m_run, mx);
            float ls = 0.f;
#pragma unroll
            for (int i = 0; i < 16; ++i) { p[i] = __expf(p[i] - m_new); ls += p[i]; }
            ls += __shfl_xor(ls, 16);
            ls += __shfl_xor(ls, 32);
            float alpha = __expf(m_run - m_new);
            l_run = l_run * alpha + ls;
            m_run = m_new;
            // pack P (4 consecutive keys) -> swizzled LDS b64 writes
#pragma unroll
            for (int mt = 0; mt < 4; ++mt) {
                ushort4 pk;
                pk.x = f2bf(p[mt * 4 + 0]); pk.y = f2bf(p[mt * 4 + 1]);
                pk.z = f2bf(p[mt * 4 + 2]); pk.w = f2bf(p[mt * 4 + 3]);
                int g = 2 * mt + (qd >> 1);
                int off = c * 64 + ((g ^ (c & 7)) << 3) + ((qd & 1) << 2);
                *(ushort4*)&Pl[w][off] = pk;
            }
            // rescale O by alpha (broadcast per output row = qd*4+r)
#pragma unroll
            for (int r = 0; r < 4; ++r) {
                float al = __shfl(alpha, qd * 4 + r);
#pragma unroll
                for (int nt = 0; nt < 4; ++nt) o[nt][r] *= al;
            }
            // P fragments back (A-layout): same-wave LDS ops are in-order, no barrier needed
            short8 pf0 = *(const short8*)&Pl[w][c * 64 + (((qd) ^ (c & 7)) << 3)];
            short8 pf1 = *(const short8*)&Pl[w][c * 64 + (((4 + qd) ^ (c & 7)) << 3)];
            // O += P*V
#pragma unroll
            for (int nt = 0; nt < 4; ++nt) {
                short8 vf0 = *(const short8*)&Vt[(nt * 16 + c) * 72 + qd * 8];
                short8 vf1 = *(const short8*)&Vt[(nt * 16 + c) * 72 + 32 + qd * 8];
                o[nt] = __builtin_amdgcn_mfma_f32_16x16x32_bf16(pf0, vf0, o[nt], 0, 0, 0);
                o[nt] = __builtin_amdgcn_mfma_f32_16x16x32_bf16(pf1, vf1, o[nt], 0, 0, 0);
            }
        }
        // normalize + write fp32 out; row = qd*4+r, col = nt*16+c (64B segments/row)
#pragma unroll
        for (int r = 0; r < 4; ++r) {
            float lr = __shfl(l_run, qd * 4 + r);
            float inv = 1.f / lr;
            size_t rowg = (size_t)(b * TT) + qbase + w * 16 + qd * 4 + r;
#pragma unroll
            for (int nt = 0; nt < 4; ++nt)
                out[rowg * 64 + nt * 16 + c] = o[nt][r] * inv;
        }
    }
}

extern "C" void kernel_launch(void* const* d_in, const int* in_sizes, int n_in,
                              void* d_out, int out_size, void* d_ws, size_t ws_size,
                              hipStream_t stream) {
    const float* x  = (const float*)d_in[0];
    const float* Wk = (const float*)d_in[1];
    const float* Wq = (const float*)d_in[2];
    const float* Wv = (const float*)d_in[3];
    float* out = (float*)d_out;

    // workspace: q,k,v bf16 [32768][64] + Wt bf16 [3][64][768]  (~12.9 MB)
    ushort* qbuf = (ushort*)d_ws;
    ushort* kbuf = qbuf + (size_t)MROWS * 64;
    ushort* vbuf = kbuf + (size_t)MROWS * 64;
    ushort* wt   = vbuf + (size_t)MROWS * 64;

    wt_kernel<<<576, 256, 0, stream>>>(Wq, Wk, Wv, wt);
    proj_kernel<<<MROWS / 64, 256, 0, stream>>>(x, wt, qbuf, kbuf, vbuf);
    attn_kernel<<<BBA * 32, 256, 0, stream>>>(qbuf, kbuf, vbuf, out);
}

// Round 2
// 270.514 us; speedup vs baseline: 1.0458x; 1.0458x over previous
//
#include <hip/hip_runtime.h>

#define TT 4096
#define CCH 768
#define HH 64
#define BBA 8
#define MROWS (BBA*TT)   // 32768
#define NCHUNK_PB 288    // chunks per batch at S=8

typedef __attribute__((ext_vector_type(8))) short short8;
typedef __attribute__((ext_vector_type(4))) float floatx4;

__device__ inline ushort f2bf(float f) {
    union { float f; unsigned u; } v; v.f = f;
    unsigned r = v.u + 0x7fffu + ((v.u >> 16) & 1u);   // RNE
    return (ushort)(r >> 16);
}

// ---- Kernel 1: Wt[3][64][768] bf16, n-major ----
__global__ __launch_bounds__(256) void wt_kernel(const float* __restrict__ Wq,
                                                 const float* __restrict__ Wk,
                                                 const float* __restrict__ Wv,
                                                 ushort* __restrict__ wt) {
    int idx = blockIdx.x * 256 + threadIdx.x;
    if (idx >= 3 * 64 * 768) return;
    int m = idx / (64 * 768);
    int r = idx - m * (64 * 768);
    int n = r / 768;
    int k = r - n * 768;
    const float* W = (m == 0) ? Wq : (m == 1) ? Wk : Wv;
    wt[idx] = f2bf(W[k * 64 + n]);
}

// ---- Kernel 2: fused QKV projection with register-prefetch double buffering ----
__global__ __launch_bounds__(256) void proj_kernel(const float* __restrict__ x,
                                                   const ushort* __restrict__ wt,
                                                   ushort* __restrict__ qb,
                                                   ushort* __restrict__ kb,
                                                   ushort* __restrict__ vb) {
    __shared__ ushort xs[64 * 40];
    __shared__ ushort ws[192 * 40];
    const int tid = threadIdx.x;
    const int w = tid >> 6, lane = tid & 63, c = lane & 15, qd = lane >> 4;
    const int rbase = blockIdx.x * 64;
    const int sr = tid >> 2;        // 0..63
    const int sc = (tid & 3) * 8;   // 0,8,16,24

    floatx4 acc[12];
#pragma unroll
    for (int nt = 0; nt < 12; ++nt) acc[nt] = (floatx4){0.f, 0.f, 0.f, 0.f};

    const float* xrow = &x[(size_t)(rbase + sr) * CCH + sc];
    const ushort* wr0 = &wt[(size_t)(0 * 64 + sr) * CCH + sc];
    const ushort* wr1 = &wt[(size_t)(1 * 64 + sr) * CCH + sc];
    const ushort* wr2 = &wt[(size_t)(2 * 64 + sr) * CCH + sc];

    // prefetch chunk 0
    float4 f0 = *(const float4*)&xrow[0];
    float4 f1 = *(const float4*)&xrow[4];
    short8 wv0 = *(const short8*)&wr0[0];
    short8 wv1 = *(const short8*)&wr1[0];
    short8 wv2 = *(const short8*)&wr2[0];

    for (int kc = 0; kc < CCH; kc += 32) {
        short8 xv;
        xv[0] = (short)f2bf(f0.x); xv[1] = (short)f2bf(f0.y);
        xv[2] = (short)f2bf(f0.z); xv[3] = (short)f2bf(f0.w);
        xv[4] = (short)f2bf(f1.x); xv[5] = (short)f2bf(f1.y);
        xv[6] = (short)f2bf(f1.z); xv[7] = (short)f2bf(f1.w);
        if (kc) __syncthreads();                 // prev iter's readers done
        *(short8*)&xs[sr * 40 + sc] = xv;
        *(short8*)&ws[(0 * 64 + sr) * 40 + sc] = wv0;
        *(short8*)&ws[(1 * 64 + sr) * 40 + sc] = wv1;
        *(short8*)&ws[(2 * 64 + sr) * 40 + sc] = wv2;
        __syncthreads();
        if (kc + 32 < CCH) {                     // prefetch next chunk under MFMAs
            f0 = *(const float4*)&xrow[kc + 32];
            f1 = *(const float4*)&xrow[kc + 36];
            wv0 = *(const short8*)&wr0[kc + 32];
            wv1 = *(const short8*)&wr1[kc + 32];
            wv2 = *(const short8*)&wr2[kc + 32];
        }
        short8 a = *(const short8*)&xs[(w * 16 + c) * 40 + qd * 8];
#pragma unroll
        for (int nt = 0; nt < 12; ++nt) {
            short8 bfr = *(const short8*)&ws[(nt * 16 + c) * 40 + qd * 8];
            acc[nt] = __builtin_amdgcn_mfma_f32_16x16x32_bf16(a, bfr, acc[nt], 0, 0, 0);
        }
    }
#pragma unroll
    for (int nt = 0; nt < 12; ++nt) {
        int ncol = nt * 16 + c;
        ushort* dst = (ncol < 64) ? qb : (ncol < 128) ? kb : vb;
        int h = ncol & 63;
#pragma unroll
        for (int r = 0; r < 4; ++r) {
            int rg = rbase + w * 16 + qd * 4 + r;
            dst[(size_t)rg * 64 + h] = f2bf(acc[nt][r]);
        }
    }
}

// ---- Kernel 3: chunked flash attention.
// mode 0: one block per (b, q-tile), full key row, direct output (fallback).
// mode 1: key-split into <=8-k-tile chunks (2304 blocks), partials (O~, m, l) to ws.
__global__ __launch_bounds__(256) void attn_kernel(const ushort* __restrict__ qb,
                                                   const ushort* __restrict__ kb,
                                                   const ushort* __restrict__ vb,
                                                   float* __restrict__ out,
                                                   float* __restrict__ Opart,
                                                   float* __restrict__ Oml,
                                                   int mode) {
    __shared__ ushort Ks[64 * 72];
    __shared__ ushort Vt[64 * 72];
    __shared__ ushort Pl[4][1024];
    const float scale = 0.03608439182435161f;   // 768^-0.5
    const int tid = threadIdx.x;
    const int w = tid >> 6, lane = tid & 63, c = lane & 15, qd = lane >> 4;
    const int bx = blockIdx.x;
    const int b = bx & 7, craw = bx >> 3;

    int qt, chunk, nch, cix;
    if (mode == 0) {
        qt = 63 - craw; nch = 1; chunk = 0; cix = qt;
    } else {
        cix = (NCHUNK_PB - 1) - craw;           // big chunks dispatch first
        int idx, s;
        if      (cix <   8) { idx = 0; s =   0; }
        else if (cix <  24) { idx = 1; s =   8; }
        else if (cix <  48) { idx = 2; s =  24; }
        else if (cix <  80) { idx = 3; s =  48; }
        else if (cix < 120) { idx = 4; s =  80; }
        else if (cix < 168) { idx = 5; s = 120; }
        else if (cix < 224) { idx = 6; s = 168; }
        else                { idx = 7; s = 224; }
        nch = idx + 1;
        int d = cix - s;
        qt = (idx << 3) + d / nch;
        chunk = d - (d / nch) * nch;
    }
    const int n = qt + 1;
    const int kbeg = chunk * n / nch;
    const int kend = (chunk + 1) * n / nch;
    const bool direct = (nch == 1);
    const int qbase = qt * 64;

    const size_t growq = (size_t)(b * TT + qbase + w * 16 + c);
    short8 qf0 = *(const short8*)&qb[growq * 64 + qd * 8];
    short8 qf1 = *(const short8*)&qb[growq * 64 + 32 + qd * 8];
    floatx4 o[4];
#pragma unroll
    for (int nt = 0; nt < 4; ++nt) o[nt] = (floatx4){0.f, 0.f, 0.f, 0.f};
    float m_run = -__builtin_inff(), l_run = 0.f;
    const int qg = qbase + w * 16 + c;

    const int sr = tid >> 2;            // K staging row
    const int sk = (tid & 3) * 16;      // K staging col
    const int vr = tid & 63;            // V staging key
    const int vc = (tid >> 6) * 16;     // V staging dim base
    const ushort* kbb = &kb[(size_t)(b * TT) * 64];
    const ushort* vbb = &vb[(size_t)(b * TT) * 64];

    // prefetch first tile
    short8 k0, k1, v0, v1;
    {
        const ushort* srcK = &kbb[((size_t)(kbeg * 64 + sr)) * 64 + sk];
        k0 = *(const short8*)srcK; k1 = *(const short8*)(srcK + 8);
        const ushort* srcV = &vbb[((size_t)(kbeg * 64 + vr)) * 64 + vc];
        v0 = *(const short8*)srcV; v1 = *(const short8*)(srcV + 8);
    }

    for (int kt = kbeg; kt < kend; ++kt) {
        __syncthreads();
        *(short8*)&Ks[sr * 72 + sk] = k0;
        *(short8*)&Ks[sr * 72 + sk + 8] = k1;
#pragma unroll
        for (int i = 0; i < 8; ++i) Vt[(vc + i) * 72 + vr] = (ushort)v0[i];
#pragma unroll
        for (int i = 0; i < 8; ++i) Vt[(vc + 8 + i) * 72 + vr] = (ushort)v1[i];
        __syncthreads();
        if (kt + 1 < kend) {            // prefetch next tile under compute
            const ushort* srcK = &kbb[((size_t)((kt + 1) * 64 + sr)) * 64 + sk];
            k0 = *(const short8*)srcK; k1 = *(const short8*)(srcK + 8);
            const ushort* srcV = &vbb[((size_t)((kt + 1) * 64 + vr)) * 64 + vc];
            v0 = *(const short8*)srcV; v1 = *(const short8*)(srcV + 8);
        }
        // S^T[key][query]
        floatx4 st[4];
#pragma unroll
        for (int mt = 0; mt < 4; ++mt) {
            short8 kf0 = *(const short8*)&Ks[(mt * 16 + c) * 72 + qd * 8];
            short8 kf1 = *(const short8*)&Ks[(mt * 16 + c) * 72 + 32 + qd * 8];
            st[mt] = (floatx4){0.f, 0.f, 0.f, 0.f};
            st[mt] = __builtin_amdgcn_mfma_f32_16x16x32_bf16(kf0, qf0, st[mt], 0, 0, 0);
            st[mt] = __builtin_amdgcn_mfma_f32_16x16x32_bf16(kf1, qf1, st[mt], 0, 0, 0);
        }
        float p[16];
#pragma unroll
        for (int mt = 0; mt < 4; ++mt)
#pragma unroll
            for (int r = 0; r < 4; ++r) {
                int key = kt * 64 + mt * 16 + qd * 4 + r;
                float v = st[mt][r] * scale;
                p[mt * 4 + r] = (key <= qg) ? v : -__builtin_inff();
            }
        float mx = p[0];
#pragma unroll
        for (int i = 1; i < 16; ++i) mx = fmaxf(mx, p[i]);
        mx = fmaxf(mx, __shfl_xor(mx, 16));
        mx = fmaxf(mx, __shfl_xor(mx, 32));
        float m_new = fmaxf(m_run, mx);
        float ls = 0.f;
#pragma unroll
        for (int i = 0; i < 16; ++i) { p[i] = __expf(p[i] - m_new); ls += p[i]; }
        ls += __shfl_xor(ls, 16);
        ls += __shfl_xor(ls, 32);
        float alpha = __expf(m_run - m_new);
        l_run = l_run * alpha + ls;
        m_run = m_new;
#pragma unroll
        for (int mt = 0; mt < 4; ++mt) {
            ushort4 pk;
            pk.x = f2bf(p[mt * 4 + 0]); pk.y = f2bf(p[mt * 4 + 1]);
            pk.z = f2bf(p[mt * 4 + 2]); pk.w = f2bf(p[mt * 4 + 3]);
            int g = 2 * mt + (qd >> 1);
            int off = c * 64 + ((g ^ (c & 7)) << 3) + ((qd & 1) << 2);
            *(ushort4*)&Pl[w][off] = pk;
        }
#pragma unroll
        for (int r = 0; r < 4; ++r) {
            float al = __shfl(alpha, qd * 4 + r);
#pragma unroll
            for (int nt = 0; nt < 4; ++nt) o[nt][r] *= al;
        }
        short8 pf0 = *(const short8*)&Pl[w][c * 64 + (((qd) ^ (c & 7)) << 3)];
        short8 pf1 = *(const short8*)&Pl[w][c * 64 + (((4 + qd) ^ (c & 7)) << 3)];
#pragma unroll
        for (int nt = 0; nt < 4; ++nt) {
            short8 vf0 = *(const short8*)&Vt[(nt * 16 + c) * 72 + qd * 8];
            short8 vf1 = *(const short8*)&Vt[(nt * 16 + c) * 72 + 32 + qd * 8];
            o[nt] = __builtin_amdgcn_mfma_f32_16x16x32_bf16(pf0, vf0, o[nt], 0, 0, 0);
            o[nt] = __builtin_amdgcn_mfma_f32_16x16x32_bf16(pf1, vf1, o[nt], 0, 0, 0);
        }
    }

    if (direct) {
#pragma unroll
        for (int r = 0; r < 4; ++r) {
            float lr = __shfl(l_run, qd * 4 + r);
            float inv = 1.f / lr;
            size_t rowg = (size_t)(b * TT) + qbase + w * 16 + qd * 4 + r;
#pragma unroll
            for (int nt = 0; nt < 4; ++nt)
                out[rowg * 64 + nt * 16 + c] = o[nt][r] * inv;
        }
    } else {
        const int slot = b * NCHUNK_PB + cix;
        float* Od = Opart + (size_t)slot * 4096;
#pragma unroll
        for (int r = 0; r < 4; ++r) {
            int row = w * 16 + qd * 4 + r;
#pragma unroll
            for (int nt = 0; nt < 4; ++nt)
                Od[row * 64 + nt * 16 + c] = o[nt][r];
        }
        if (qd == 0) {
            Oml[(size_t)slot * 128 + w * 16 + c] = m_run;
            Oml[(size_t)slot * 128 + 64 + w * 16 + c] = l_run;
        }
    }
}

// ---- Kernel 4: combine partials for qt >= 8 (nch >= 2) ----
__global__ __launch_bounds__(256) void combine_kernel(const float* __restrict__ Opart,
                                                      const float* __restrict__ Oml,
                                                      float* __restrict__ out) {
    const int b = blockIdx.x & 7;
    const int qt = 8 + (blockIdx.x >> 3);
    const int idx = qt >> 3;   // 1..7
    int s;
    if      (idx == 1) s = 8;
    else if (idx == 2) s = 24;
    else if (idx == 3) s = 48;
    else if (idx == 4) s = 80;
    else if (idx == 5) s = 120;
    else if (idx == 6) s = 168;
    else               s = 224;
    const int nch = idx + 1;
    const int c0 = s + (qt - (idx << 3)) * nch;
    const size_t slot0 = (size_t)(b * NCHUNK_PB + c0);
    const int t = threadIdx.x;
    const int col = t & 63, r0 = t >> 6;

    for (int rr = 0; rr < 16; ++rr) {
        int row = (rr << 2) + r0;
        float M = -__builtin_inff();
        for (int i = 0; i < nch; ++i)
            M = fmaxf(M, Oml[(slot0 + i) * 128 + row]);
        float S = 0.f, A = 0.f;
        for (int i = 0; i < nch; ++i) {
            float wgt = __expf(Oml[(slot0 + i) * 128 + row] - M);
            S += wgt * Oml[(slot0 + i) * 128 + 64 + row];
            A += wgt * Opart[(slot0 + i) * 4096 + row * 64 + col];
        }
        out[((size_t)(b * TT) + qt * 64 + row) * 64 + col] = A / S;
    }
}

extern "C" void kernel_launch(void* const* d_in, const int* in_sizes, int n_in,
                              void* d_out, int out_size, void* d_ws, size_t ws_size,
                              hipStream_t stream) {
    const float* x  = (const float*)d_in[0];
    const float* Wk = (const float*)d_in[1];
    const float* Wq = (const float*)d_in[2];
    const float* Wv = (const float*)d_in[3];
    float* out = (float*)d_out;

    // ws layout: q,k,v bf16 [32768][64] + Wt bf16 [3][64][768] + partials
    ushort* qbuf = (ushort*)d_ws;
    ushort* kbuf = qbuf + (size_t)MROWS * 64;
    ushort* vbuf = kbuf + (size_t)MROWS * 64;
    ushort* wt   = vbuf + (size_t)MROWS * 64;
    const size_t base = (size_t)MROWS * 64 * 3 * 2 + (size_t)3 * 64 * CCH * 2;  // 12,877,824
    float* Opart = (float*)((char*)d_ws + base);
    float* Oml   = (float*)((char*)d_ws + base + (size_t)BBA * NCHUNK_PB * 4096 * 4);
    const size_t need = base + (size_t)BBA * NCHUNK_PB * 4096 * 4
                             + (size_t)BBA * NCHUNK_PB * 128 * 4;   // ~51.8 MB
    const int split = (ws_size >= need) ? 1 : 0;

    wt_kernel<<<576, 256, 0, stream>>>(Wq, Wk, Wv, wt);
    proj_kernel<<<MROWS / 64, 256, 0, stream>>>(x, wt, qbuf, kbuf, vbuf);
    if (split) {
        attn_kernel<<<BBA * NCHUNK_PB, 256, 0, stream>>>(qbuf, kbuf, vbuf, out, Opart, Oml, 1);
        combine_kernel<<<BBA * 56, 256, 0, stream>>>(Opart, Oml, out);
    } else {
        attn_kernel<<<BBA * 64, 256, 0, stream>>>(qbuf, kbuf, vbuf, out, Opart, Oml, 0);
    }
}

// Round 3
// 269.291 us; speedup vs baseline: 1.0506x; 1.0045x over previous
//
#include <hip/hip_runtime.h>

#define TT 4096
#define CCH 768
#define HH 64
#define BBA 8
#define MROWS (BBA*TT)   // 32768
#define NCHUNK_PB 288    // chunks per batch at S<=8

typedef __attribute__((ext_vector_type(8))) short short8;
typedef __attribute__((ext_vector_type(4))) float floatx4;
#if __has_builtin(__builtin_amdgcn_cvt_pk_bf16_f32)
typedef __attribute__((ext_vector_type(2))) __bf16 bf16x2;
#endif

__device__ inline ushort f2bf(float f) {
    union { float f; unsigned u; } v; v.f = f;
    unsigned r = v.u + 0x7fffu + ((v.u >> 16) & 1u);   // RNE
    return (ushort)(r >> 16);
}

// pack 2 fp32 -> 2 bf16 in one dword (v_cvt_pk_bf16_f32 on gfx950)
__device__ inline unsigned pk_bf16(float a, float b) {
#if __has_builtin(__builtin_amdgcn_cvt_pk_bf16_f32)
    union { bf16x2 v; unsigned u; } cv;
    cv.v = __builtin_amdgcn_cvt_pk_bf16_f32(a, b);
    return cv.u;
#else
    union { float f; unsigned u; } x, y; x.f = a; y.f = b;
    unsigned ra = x.u + 0x7fffu + ((x.u >> 16) & 1u);
    unsigned rb = y.u + 0x7fffu + ((y.u >> 16) & 1u);
    return (ra >> 16) | (rb & 0xffff0000u);
#endif
}

__device__ inline float fast_exp2(float x) {
#if __has_builtin(__builtin_amdgcn_exp2f)
    return __builtin_amdgcn_exp2f(x);
#else
    return exp2f(x);
#endif
}

// ---- Kernel 1: Wt[3][64][768] bf16, n-major, via LDS transpose (both sides coalesced) ----
__global__ __launch_bounds__(256) void wt_kernel(const float* __restrict__ Wq,
                                                 const float* __restrict__ Wk,
                                                 const float* __restrict__ Wv,
                                                 ushort* __restrict__ wt) {
    __shared__ float tile[64][65];
    const int m = blockIdx.x / 12, kt = blockIdx.x % 12;
    const float* W = (m == 0) ? Wq : (m == 1) ? Wk : Wv;
    const int n = threadIdx.x & 63, r0 = threadIdx.x >> 6;
#pragma unroll
    for (int i = 0; i < 16; ++i) {
        int k = r0 * 16 + i;
        tile[k][n] = W[(kt * 64 + k) * 64 + n];
    }
    __syncthreads();
    const int k2 = threadIdx.x & 63, n2 = threadIdx.x >> 6;
#pragma unroll
    for (int i = 0; i < 16; ++i) {
        int nn = n2 * 16 + i;
        wt[(m * 64 + nn) * 768 + kt * 64 + k2] = f2bf(tile[k2][nn]);
    }
}

// ---- Kernel 2: fused QKV projection (round-1 structure: known-good ~26us).
// q,k row-major [t][64]; V written TRANSPOSED [b][64][4096] for attn staging.
__global__ __launch_bounds__(256) void proj_kernel(const float* __restrict__ x,
                                                   const ushort* __restrict__ wt,
                                                   ushort* __restrict__ qb,
                                                   ushort* __restrict__ kb,
                                                   ushort* __restrict__ vtg) {
    __shared__ ushort xs[64 * 40];
    __shared__ ushort ws[192 * 40];
    const int tid = threadIdx.x;
    const int w = tid >> 6, lane = tid & 63, c = lane & 15, qd = lane >> 4;
    const int rbase = blockIdx.x * 64;
    const int sr = tid >> 2;        // 0..63
    const int sc = (tid & 3) * 8;   // 0,8,16,24

    floatx4 acc[12];
#pragma unroll
    for (int nt = 0; nt < 12; ++nt) acc[nt] = (floatx4){0.f, 0.f, 0.f, 0.f};

    for (int kc = 0; kc < CCH; kc += 32) {
        {   // stage x chunk (fp32 -> bf16, packed cvt)
            const float* src = &x[(size_t)(rbase + sr) * CCH + kc + sc];
            float4 f0 = *(const float4*)src;
            float4 f1 = *(const float4*)(src + 4);
            uint4 xv;
            xv.x = pk_bf16(f0.x, f0.y); xv.y = pk_bf16(f0.z, f0.w);
            xv.z = pk_bf16(f1.x, f1.y); xv.w = pk_bf16(f1.z, f1.w);
            *(uint4*)&xs[sr * 40 + sc] = xv;
        }
#pragma unroll
        for (int i = 0; i < 3; ++i) {   // stage Wt chunk
            int row = i * 64 + sr;
            short8 wv = *(const short8*)&wt[(size_t)row * CCH + kc + sc];
            *(short8*)&ws[row * 40 + sc] = wv;
        }
        __syncthreads();
        short8 a = *(const short8*)&xs[(w * 16 + c) * 40 + qd * 8];
#pragma unroll
        for (int nt = 0; nt < 12; ++nt) {
            short8 bfr = *(const short8*)&ws[(nt * 16 + c) * 40 + qd * 8];
            acc[nt] = __builtin_amdgcn_mfma_f32_16x16x32_bf16(a, bfr, acc[nt], 0, 0, 0);
        }
        __syncthreads();
    }
    // epilogue: q,k row-major; v transposed [b][h][t] with 8B vector stores
#pragma unroll
    for (int nt = 0; nt < 8; ++nt) {
        int ncol = nt * 16 + c;
        ushort* dst = (ncol < 64) ? qb : kb;
        int h = ncol & 63;
#pragma unroll
        for (int r = 0; r < 4; ++r) {
            int rg = rbase + w * 16 + qd * 4 + r;
            dst[(size_t)rg * 64 + h] = f2bf(acc[nt][r]);
        }
    }
    const int bb = rbase >> 12;
    const int tbase = (rbase & 4095) + w * 16 + qd * 4;
#pragma unroll
    for (int nt = 8; nt < 12; ++nt) {
        int h = (nt - 8) * 16 + c;
        uint2 val;
        val.x = pk_bf16(acc[nt][0], acc[nt][1]);
        val.y = pk_bf16(acc[nt][2], acc[nt][3]);
        *(uint2*)&vtg[((size_t)(bb * 64 + h)) * 4096 + tbase] = val;
    }
}

// ---- Kernel 3: chunked flash attention (exp2-domain softmax, diag-only masking).
__global__ __launch_bounds__(256) void attn_kernel(const ushort* __restrict__ qb,
                                                   const ushort* __restrict__ kb,
                                                   const ushort* __restrict__ vtg,
                                                   float* __restrict__ out,
                                                   float* __restrict__ Opart,
                                                   float* __restrict__ Oml,
                                                   int mode) {
    __shared__ ushort Ks[64 * 72];      // [key][dim]
    __shared__ ushort Vt[64 * 72];      // [dim][key]
    __shared__ ushort Pl[4][1024];
    const float scale2 = 0.052058773f;  // 768^-0.5 * log2(e)
    const int tid = threadIdx.x;
    const int w = tid >> 6, lane = tid & 63, c = lane & 15, qd = lane >> 4;
    const int bx = blockIdx.x;
    const int b = bx & 7, craw = bx >> 3;

    int qt, chunk, nch, cix;
    if (mode == 0) {
        qt = 63 - craw; nch = 1; chunk = 0; cix = qt;
    } else {
        cix = (NCHUNK_PB - 1) - craw;           // big chunks dispatch first
        int idx, s;
        if      (cix <   8) { idx = 0; s =   0; }
        else if (cix <  24) { idx = 1; s =   8; }
        else if (cix <  48) { idx = 2; s =  24; }
        else if (cix <  80) { idx = 3; s =  48; }
        else if (cix < 120) { idx = 4; s =  80; }
        else if (cix < 168) { idx = 5; s = 120; }
        else if (cix < 224) { idx = 6; s = 168; }
        else                { idx = 7; s = 224; }
        nch = idx + 1;
        int d = cix - s;
        qt = (idx << 3) + d / nch;
        chunk = d - (d / nch) * nch;
    }
    const int n = qt + 1;
    const int kbeg = chunk * n / nch;
    const int kend = (chunk + 1) * n / nch;
    const bool direct = (nch == 1);
    const int qbase = qt * 64;

    const size_t growq = (size_t)(b * TT + qbase + w * 16 + c);
    short8 qf0 = *(const short8*)&qb[growq * 64 + qd * 8];
    short8 qf1 = *(const short8*)&qb[growq * 64 + 32 + qd * 8];
    floatx4 o[4];
#pragma unroll
    for (int nt = 0; nt < 4; ++nt) o[nt] = (floatx4){0.f, 0.f, 0.f, 0.f};
    float m_run = -__builtin_inff(), l_run = 0.f;

    const int sr = tid >> 2;            // K staging: key row
    const int sk = (tid & 3) * 16;      // K staging: dim offset
    const int vd = tid >> 2;            // V staging: dim row
    const int vk = (tid & 3) * 16;      // V staging: key offset
    const ushort* kbb = &kb[(size_t)(b * TT) * 64];
    const ushort* vbb = &vtg[(size_t)(b * 64) * 4096];

    // prefetch first tile
    short8 k0, k1, v0, v1;
    {
        const ushort* srcK = &kbb[((size_t)(kbeg * 64 + sr)) * 64 + sk];
        k0 = *(const short8*)srcK; k1 = *(const short8*)(srcK + 8);
        const ushort* srcV = &vbb[(size_t)vd * 4096 + kbeg * 64 + vk];
        v0 = *(const short8*)srcV; v1 = *(const short8*)(srcV + 8);
    }

    for (int kt = kbeg; kt < kend; ++kt) {
        __syncthreads();
        *(short8*)&Ks[sr * 72 + sk] = k0;
        *(short8*)&Ks[sr * 72 + sk + 8] = k1;
        *(short8*)&Vt[vd * 72 + vk] = v0;
        *(short8*)&Vt[vd * 72 + vk + 8] = v1;
        __syncthreads();
        if (kt + 1 < kend) {            // prefetch next tile under compute
            const ushort* srcK = &kbb[((size_t)((kt + 1) * 64 + sr)) * 64 + sk];
            k0 = *(const short8*)srcK; k1 = *(const short8*)(srcK + 8);
            const ushort* srcV = &vbb[(size_t)vd * 4096 + (kt + 1) * 64 + vk];
            v0 = *(const short8*)srcV; v1 = *(const short8*)(srcV + 8);
        }
        // S^T[key][query]
        floatx4 st[4];
#pragma unroll
        for (int mt = 0; mt < 4; ++mt) {
            short8 kf0 = *(const short8*)&Ks[(mt * 16 + c) * 72 + qd * 8];
            short8 kf1 = *(const short8*)&Ks[(mt * 16 + c) * 72 + 32 + qd * 8];
            st[mt] = (floatx4){0.f, 0.f, 0.f, 0.f};
            st[mt] = __builtin_amdgcn_mfma_f32_16x16x32_bf16(kf0, qf0, st[mt], 0, 0, 0);
            st[mt] = __builtin_amdgcn_mfma_f32_16x16x32_bf16(kf1, qf1, st[mt], 0, 0, 0);
        }
        float p[16];
#pragma unroll
        for (int mt = 0; mt < 4; ++mt)
#pragma unroll
            for (int r = 0; r < 4; ++r)
                p[mt * 4 + r] = st[mt][r] * scale2;     // exp2 domain
        if (kt == qt) {                                  // diagonal tile only (uniform branch)
            const int thr = w * 16 + c;
#pragma unroll
            for (int mt = 0; mt < 4; ++mt)
#pragma unroll
                for (int r = 0; r < 4; ++r) {
                    int kl = mt * 16 + qd * 4 + r;
                    if (kl > thr) p[mt * 4 + r] = -__builtin_inff();
                }
        }
        float mx = p[0];
#pragma unroll
        for (int i = 1; i < 16; ++i) mx = fmaxf(mx, p[i]);
        mx = fmaxf(mx, __shfl_xor(mx, 16));
        mx = fmaxf(mx, __shfl_xor(mx, 32));
        float m_new = fmaxf(m_run, mx);
        float ls = 0.f;
#pragma unroll
        for (int i = 0; i < 16; ++i) { p[i] = fast_exp2(p[i] - m_new); ls += p[i]; }
        ls += __shfl_xor(ls, 16);
        ls += __shfl_xor(ls, 32);
        float alpha = fast_exp2(m_run - m_new);
        l_run = l_run * alpha + ls;
        m_run = m_new;
#pragma unroll
        for (int mt = 0; mt < 4; ++mt) {
            uint2 pk;
            pk.x = pk_bf16(p[mt * 4 + 0], p[mt * 4 + 1]);
            pk.y = pk_bf16(p[mt * 4 + 2], p[mt * 4 + 3]);
            int g = 2 * mt + (qd >> 1);
            int off = c * 64 + ((g ^ (c & 7)) << 3) + ((qd & 1) << 2);
            *(uint2*)&Pl[w][off] = pk;
        }
#pragma unroll
        for (int r = 0; r < 4; ++r) {
            float al = __shfl(alpha, qd * 4 + r);
#pragma unroll
            for (int nt = 0; nt < 4; ++nt) o[nt][r] *= al;
        }
        short8 pf0 = *(const short8*)&Pl[w][c * 64 + (((qd) ^ (c & 7)) << 3)];
        short8 pf1 = *(const short8*)&Pl[w][c * 64 + (((4 + qd) ^ (c & 7)) << 3)];
#pragma unroll
        for (int nt = 0; nt < 4; ++nt) {
            short8 vf0 = *(const short8*)&Vt[(nt * 16 + c) * 72 + qd * 8];
            short8 vf1 = *(const short8*)&Vt[(nt * 16 + c) * 72 + 32 + qd * 8];
            o[nt] = __builtin_amdgcn_mfma_f32_16x16x32_bf16(pf0, vf0, o[nt], 0, 0, 0);
            o[nt] = __builtin_amdgcn_mfma_f32_16x16x32_bf16(pf1, vf1, o[nt], 0, 0, 0);
        }
    }

    if (direct) {
#pragma unroll
        for (int r = 0; r < 4; ++r) {
            float lr = __shfl(l_run, qd * 4 + r);
            float inv = 1.f / lr;
            size_t rowg = (size_t)(b * TT) + qbase + w * 16 + qd * 4 + r;
#pragma unroll
            for (int nt = 0; nt < 4; ++nt)
                out[rowg * 64 + nt * 16 + c] = o[nt][r] * inv;
        }
    } else {
        const int slot = b * NCHUNK_PB + cix;
        float* Od = Opart + (size_t)slot * 4096;
#pragma unroll
        for (int r = 0; r < 4; ++r) {
            int row = w * 16 + qd * 4 + r;
#pragma unroll
            for (int nt = 0; nt < 4; ++nt)
                Od[row * 64 + nt * 16 + c] = o[nt][r];
        }
        if (qd == 0) {
            Oml[(size_t)slot * 128 + w * 16 + c] = m_run;
            Oml[(size_t)slot * 128 + 64 + w * 16 + c] = l_run;
        }
    }
}

// ---- Kernel 4: combine partials for qt >= 8 (nch >= 2); exp2 domain ----
__global__ __launch_bounds__(256) void combine_kernel(const float* __restrict__ Opart,
                                                      const float* __restrict__ Oml,
                                                      float* __restrict__ out) {
    const int b = blockIdx.x & 7;
    const int qt = 8 + (blockIdx.x >> 3);
    const int idx = qt >> 3;   // 1..7
    int s;
    if      (idx == 1) s = 8;
    else if (idx == 2) s = 24;
    else if (idx == 3) s = 48;
    else if (idx == 4) s = 80;
    else if (idx == 5) s = 120;
    else if (idx == 6) s = 168;
    else               s = 224;
    const int nch = idx + 1;
    const int c0 = s + (qt - (idx << 3)) * nch;
    const size_t slot0 = (size_t)(b * NCHUNK_PB + c0);
    const int t = threadIdx.x;
    const int col = t & 63, r0 = t >> 6;

    for (int rr = 0; rr < 16; ++rr) {
        int row = (rr << 2) + r0;
        float M = -__builtin_inff();
        for (int i = 0; i < nch; ++i)
            M = fmaxf(M, Oml[(slot0 + i) * 128 + row]);
        float S = 0.f, A = 0.f;
        for (int i = 0; i < nch; ++i) {
            float wgt = fast_exp2(Oml[(slot0 + i) * 128 + row] - M);
            S += wgt * Oml[(slot0 + i) * 128 + 64 + row];
            A += wgt * Opart[(slot0 + i) * 4096 + row * 64 + col];
        }
        out[((size_t)(b * TT) + qt * 64 + row) * 64 + col] = A / S;
    }
}

extern "C" void kernel_launch(void* const* d_in, const int* in_sizes, int n_in,
                              void* d_out, int out_size, void* d_ws, size_t ws_size,
                              hipStream_t stream) {
    const float* x  = (const float*)d_in[0];
    const float* Wk = (const float*)d_in[1];
    const float* Wq = (const float*)d_in[2];
    const float* Wv = (const float*)d_in[3];
    float* out = (float*)d_out;

    // ws layout: q,k bf16 [32768][64]; v^T bf16 [8][64][4096]; Wt; partials
    ushort* qbuf = (ushort*)d_ws;
    ushort* kbuf = qbuf + (size_t)MROWS * 64;
    ushort* vbuf = kbuf + (size_t)MROWS * 64;   // transposed layout, same footprint
    ushort* wt   = vbuf + (size_t)MROWS * 64;
    const size_t base = (size_t)MROWS * 64 * 3 * 2 + (size_t)3 * 64 * CCH * 2;  // 12,877,824
    float* Opart = (float*)((char*)d_ws + base);
    float* Oml   = (float*)((char*)d_ws + base + (size_t)BBA * NCHUNK_PB * 4096 * 4);
    const size_t need = base + (size_t)BBA * NCHUNK_PB * 4096 * 4
                             + (size_t)BBA * NCHUNK_PB * 128 * 4;   // ~51.8 MB
    const int split = (ws_size >= need) ? 1 : 0;

    wt_kernel<<<36, 256, 0, stream>>>(Wq, Wk, Wv, wt);
    proj_kernel<<<MROWS / 64, 256, 0, stream>>>(x, wt, qbuf, kbuf, vbuf);
    if (split) {
        attn_kernel<<<BBA * NCHUNK_PB, 256, 0, stream>>>(qbuf, kbuf, vbuf, out, Opart, Oml, 1);
        combine_kernel<<<BBA * 56, 256, 0, stream>>>(Opart, Oml, out);
    } else {
        attn_kernel<<<BBA * 64, 256, 0, stream>>>(qbuf, kbuf, vbuf, out, Opart, Oml, 0);
    }
}